// Round 1
// baseline (465.608 us; speedup 1.0000x reference)
//
#include <hip/hip_runtime.h>

// Problem constants: B=512, D=1024, H1=512, H2=128
// Outputs (f32, concat): recover [512,1024], c2 [512,128], Jac [512,128,1024]
//
// Plan:
//  prep:    W1 [512,1024] f32 -> W1T [1024,512] f16 (transposed); W2 -> f16
//  gemm_f32<sig>: c1 = sigmoid(x@W1^T+b1), s1p        (fp32 for accuracy)
//  gemm_f32<sig>: c2 = sigmoid(c1@W2^T+b2) -> out, s2p (fp32 for accuracy)
//  gemm_f32<sig->f16>: c3h = f16(sigmoid(c2@W2+b3))
//  recover_kernel (MFMA f16): recover = c3@W1 + b_r   -> out
//  jac_kernel (MFMA f16): Jac[b] = diag(s2p[b]) (W2 . s1p[b]) W1  -> out
//    A-tile = W2h * s1p (packed f16 mul, manual LDS stage)
//    B-tile = W1T rows via __builtin_amdgcn_global_load_lds width=16 (m97 pattern)

typedef _Float16 f16x8 __attribute__((ext_vector_type(8)));
typedef _Float16 f16x4 __attribute__((ext_vector_type(4)));
typedef float    f32x4 __attribute__((ext_vector_type(4)));

__device__ __forceinline__ void gld_lds16(const _Float16* src, _Float16* dst_wave_uniform) {
    // async global->LDS, 16B per lane; LDS dest = wave-uniform base + lane*16
    __builtin_amdgcn_global_load_lds((const __attribute__((address_space(1))) unsigned int*)src,
                                     (__attribute__((address_space(3))) unsigned int*)dst_wave_uniform,
                                     16, 0, 0);
}

// ---------------- prep: W1 transpose->f16, W2 ->f16 ----------------
__global__ __launch_bounds__(256) void prep_kernel(const float* __restrict__ W1,
                                                   const float* __restrict__ W2,
                                                   _Float16* __restrict__ W1T,   // [1024][512]
                                                   _Float16* __restrict__ W2h) { // [128][512]
    int bx = blockIdx.x;
    if (bx < 512) {
        // 32x32 tiled transpose: W1T[d][k] = W1[k][d]
        __shared__ float tile[32][33];
        int dt = (bx & 31) * 32, kt = (bx >> 5) * 32;
        int tx = threadIdx.x & 31, ty = threadIdx.x >> 5;  // 32 x 8
        #pragma unroll
        for (int r = 0; r < 32; r += 8)
            tile[ty + r][tx] = W1[(kt + ty + r) * 1024 + dt + tx];
        __syncthreads();
        #pragma unroll
        for (int r = 0; r < 32; r += 8)
            W1T[(size_t)(dt + ty + r) * 512 + kt + tx] = (_Float16)tile[tx][ty + r];
    } else {
        int i = (bx - 512) * 1024 + threadIdx.x * 4;  // 64 blocks cover 65536
        f32x4 v = *(const f32x4*)(W2 + i);
        f16x4 h;
        h.x = (_Float16)v.x; h.y = (_Float16)v.y; h.z = (_Float16)v.z; h.w = (_Float16)v.w;
        *(f16x4*)(W2h + i) = h;
    }
}

// ---------------- small fp32 GEMMs (accuracy-critical path) ----------------
// C[m][n] = epi( sum_k A[m][k]*B(k,n) + bias[n] )
// TRANSB=true : B is [N][K] row-major (C = A@B^T).  TRANSB=false: B is [K][N].
// EPI: 1 = sigmoid -> C (f32) + Cd = s(1-s);  2 = sigmoid -> Ch (f16)
template <int EPI, bool TRANSB>
__global__ __launch_bounds__(256) void gemm_f32(const float* __restrict__ A,
                                                const float* __restrict__ Bm,
                                                const float* __restrict__ bias,
                                                float* __restrict__ C,
                                                float* __restrict__ Cd,
                                                _Float16* __restrict__ Ch,
                                                int M, int N, int K) {
    __shared__ __align__(16) float As[16][68];  // [k][m], padded
    __shared__ __align__(16) float Bs[16][68];  // [k][n], padded
    const int n0 = blockIdx.x * 64, m0 = blockIdx.y * 64;
    const int tid = threadIdx.x, tx = tid & 15, ty = tid >> 4;
    float acc[4][4] = {};

    for (int k0 = 0; k0 < K; k0 += 16) {
        #pragma unroll
        for (int r = 0; r < 4; ++r) {
            int m = (tid >> 4) + r * 16, k = tid & 15;
            As[k][m] = A[(size_t)(m0 + m) * K + k0 + k];
        }
        if (TRANSB) {
            #pragma unroll
            for (int r = 0; r < 4; ++r) {
                int n = (tid >> 4) + r * 16, k = tid & 15;
                Bs[k][n] = Bm[(size_t)(n0 + n) * K + k0 + k];
            }
        } else {
            #pragma unroll
            for (int r = 0; r < 4; ++r) {
                int k = (tid >> 6) + r * 4, n = tid & 63;
                Bs[k][n] = Bm[(size_t)(k0 + k) * N + n0 + n];
            }
        }
        __syncthreads();
        #pragma unroll
        for (int k = 0; k < 16; ++k) {
            f32x4 av = *(const f32x4*)&As[k][ty * 4];
            f32x4 bv = *(const f32x4*)&Bs[k][tx * 4];
            #pragma unroll
            for (int i = 0; i < 4; ++i)
                #pragma unroll
                for (int j = 0; j < 4; ++j)
                    acc[i][j] += av[i] * bv[j];
        }
        __syncthreads();
    }

    #pragma unroll
    for (int i = 0; i < 4; ++i) {
        int row = m0 + ty * 4 + i;
        #pragma unroll
        for (int j = 0; j < 4; ++j) {
            int col = n0 + tx * 4 + j;
            float z = acc[i][j] + bias[col];
            float s = 1.f / (1.f + __expf(-z));
            if constexpr (EPI == 1) {
                C[(size_t)row * N + col]  = s;
                Cd[(size_t)row * N + col] = s * (1.f - s);
            } else {
                Ch[(size_t)row * N + col] = (_Float16)s;
            }
        }
    }
}

// ---------------- recover: MFMA f16 GEMM, M=512 N=1024 K=512 ----------------
// Out[m][n] = sum_k Ah[m][k] * W1T[n][k] + br[n]
__global__ __launch_bounds__(256) void recover_kernel(const _Float16* __restrict__ Ah,   // [512][512]
                                                      const _Float16* __restrict__ W1T,  // [1024][512]
                                                      const float* __restrict__ br,
                                                      float* __restrict__ Out) {
    __shared__ __align__(16) _Float16 Asl[128 * 64];  // [m][k]
    __shared__ __align__(16) _Float16 Bsl[128 * 64];  // [n][k]
    __shared__ float Bias[128];
    const int m0 = blockIdx.y * 128, n0 = blockIdx.x * 128;
    const int tid = threadIdx.x;
    const int lane = tid & 63, wave = tid >> 6;
    const int wm = (wave >> 1) * 64, wn = (wave & 1) * 64;
    const int l15 = lane & 15, q = lane >> 4;

    if (tid < 128) Bias[tid] = br[n0 + tid];

    f32x4 acc[4][4];
    #pragma unroll
    for (int i = 0; i < 4; ++i)
        #pragma unroll
        for (int j = 0; j < 4; ++j) acc[i][j] = (f32x4){0.f, 0.f, 0.f, 0.f};

    const int rbase = wave * 8 + (lane >> 3);
    const int kof   = (lane & 7) * 8;

    for (int k0 = 0; k0 < 512; k0 += 64) {
        #pragma unroll
        for (int r = 0; r < 4; ++r) {
            gld_lds16(Ah  + (size_t)(m0 + r * 32 + rbase) * 512 + k0 + kof, Asl + (r * 32 + wave * 8) * 64);
            gld_lds16(W1T + (size_t)(n0 + r * 32 + rbase) * 512 + k0 + kof, Bsl + (r * 32 + wave * 8) * 64);
        }
        __syncthreads();
        #pragma unroll
        for (int kk = 0; kk < 64; kk += 32) {
            f16x8 af[4], bf[4];
            #pragma unroll
            for (int i = 0; i < 4; ++i)
                af[i] = *(const f16x8*)(Asl + (wm + i * 16 + l15) * 64 + kk + q * 8);
            #pragma unroll
            for (int j = 0; j < 4; ++j)
                bf[j] = *(const f16x8*)(Bsl + (wn + j * 16 + l15) * 64 + kk + q * 8);
            #pragma unroll
            for (int i = 0; i < 4; ++i)
                #pragma unroll
                for (int j = 0; j < 4; ++j)
                    acc[i][j] = __builtin_amdgcn_mfma_f32_16x16x32_f16(af[i], bf[j], acc[i][j], 0, 0, 0);
        }
        __syncthreads();
    }

    #pragma unroll
    for (int i = 0; i < 4; ++i) {
        #pragma unroll
        for (int rg = 0; rg < 4; ++rg) {
            int m = m0 + wm + i * 16 + q * 4 + rg;
            #pragma unroll
            for (int j = 0; j < 4; ++j) {
                int dcol = wn + j * 16 + l15;
                Out[(size_t)m * 1024 + n0 + dcol] = acc[i][j][rg] + Bias[dcol];
            }
        }
    }
}

// ---------------- Jacobian: per-batch MFMA GEMM ----------------
// Jac[b][h][d] = s2p[b][h] * sum_k (W2h[h][k]*s1p[b][k]) * W1T[d][k]
// grid (8 n-tiles, 512 batches), block 256
__global__ __launch_bounds__(256) void jac_kernel(const _Float16* __restrict__ W2h,  // [128][512]
                                                  const _Float16* __restrict__ W1T,  // [1024][512]
                                                  const float* __restrict__ s1p,     // [512][512]
                                                  const float* __restrict__ s2p,     // [512][128]
                                                  float* __restrict__ Jac) {         // [512][128][1024]
    __shared__ __align__(16) _Float16 Asl[128 * 64];  // [h][k]
    __shared__ __align__(16) _Float16 Bsl[128 * 64];  // [d][k]
    __shared__ float Ssl[128];
    const int b  = blockIdx.y;
    const int n0 = blockIdx.x * 128;
    const int tid = threadIdx.x;
    const int lane = tid & 63, wave = tid >> 6;
    const int wm = (wave >> 1) * 64, wn = (wave & 1) * 64;
    const int l15 = lane & 15, q = lane >> 4;

    if (tid < 128) Ssl[tid] = s2p[b * 128 + tid];

    f32x4 acc[4][4];
    #pragma unroll
    for (int i = 0; i < 4; ++i)
        #pragma unroll
        for (int j = 0; j < 4; ++j) acc[i][j] = (f32x4){0.f, 0.f, 0.f, 0.f};

    const int ah  = tid >> 4;         // A-stage row base 0..15
    const int akq = (tid & 15) * 4;   // A-stage k offset
    const int rbase = wave * 8 + (lane >> 3);
    const int kof   = (lane & 7) * 8;

    for (int k0 = 0; k0 < 512; k0 += 64) {
        // --- A stage: (W2h row) * s1p[b] cols, packed f16 mul ---
        f32x4 s4 = *(const f32x4*)(s1p + (size_t)b * 512 + k0 + akq);
        f16x4 s4h;
        s4h.x = (_Float16)s4.x; s4h.y = (_Float16)s4.y;
        s4h.z = (_Float16)s4.z; s4h.w = (_Float16)s4.w;
        #pragma unroll
        for (int r = 0; r < 8; ++r) {
            int h = ah + r * 16;
            f16x4 w4 = *(const f16x4*)(W2h + (size_t)h * 512 + k0 + akq);
            *(f16x4*)(Asl + h * 64 + akq) = w4 * s4h;   // v_pk_mul_f16
        }
        // --- B stage: W1T rows via async global->LDS (16B/lane) ---
        #pragma unroll
        for (int r = 0; r < 4; ++r)
            gld_lds16(W1T + (size_t)(n0 + r * 32 + rbase) * 512 + k0 + kof,
                      Bsl + (r * 32 + wave * 8) * 64);
        __syncthreads();

        #pragma unroll
        for (int kk = 0; kk < 64; kk += 32) {
            f16x8 af[4], bf[4];
            #pragma unroll
            for (int i = 0; i < 4; ++i)
                af[i] = *(const f16x8*)(Asl + (wm + i * 16 + l15) * 64 + kk + q * 8);
            #pragma unroll
            for (int j = 0; j < 4; ++j)
                bf[j] = *(const f16x8*)(Bsl + (wn + j * 16 + l15) * 64 + kk + q * 8);
            #pragma unroll
            for (int i = 0; i < 4; ++i)
                #pragma unroll
                for (int j = 0; j < 4; ++j)
                    acc[i][j] = __builtin_amdgcn_mfma_f32_16x16x32_f16(af[i], bf[j], acc[i][j], 0, 0, 0);
        }
        __syncthreads();
    }

    float* outb = Jac + (size_t)b * (128 * 1024);
    #pragma unroll
    for (int i = 0; i < 4; ++i) {
        #pragma unroll
        for (int rg = 0; rg < 4; ++rg) {
            int h = wm + i * 16 + q * 4 + rg;
            float s = Ssl[h];
            #pragma unroll
            for (int j = 0; j < 4; ++j) {
                int d = n0 + wn + j * 16 + l15;
                outb[(size_t)h * 1024 + d] = acc[i][j][rg] * s;
            }
        }
    }
}

extern "C" void kernel_launch(void* const* d_in, const int* in_sizes, int n_in,
                              void* d_out, int out_size, void* d_ws, size_t ws_size,
                              hipStream_t stream) {
    const float* x  = (const float*)d_in[0];
    const float* W1 = (const float*)d_in[1];
    const float* b1 = (const float*)d_in[2];
    const float* W2 = (const float*)d_in[3];
    const float* b2 = (const float*)d_in[4];
    const float* b3 = (const float*)d_in[5];
    const float* br = (const float*)d_in[6];

    float* out_rec = (float*)d_out;               // 512*1024
    float* out_c2  = out_rec + 512 * 1024;        // 512*128
    float* out_jac = out_c2 + 512 * 128;          // 512*128*1024

    char* ws = (char*)d_ws;
    _Float16* W1T = (_Float16*)(ws);              // 1 MB   [1024][512]
    _Float16* W2h = (_Float16*)(ws + 0x100000);   // 128 KB [128][512]
    float*    c1  = (float*)(ws + 0x120000);      // 1 MB
    float*    s1p = (float*)(ws + 0x220000);      // 1 MB
    float*    s2p = (float*)(ws + 0x320000);      // 256 KB
    _Float16* c3h = (_Float16*)(ws + 0x360000);   // 512 KB

    prep_kernel<<<576, 256, 0, stream>>>(W1, W2, W1T, W2h);
    gemm_f32<1, true ><<<dim3(8, 8), 256, 0, stream>>>(x,      W1, b1, c1,     s1p, nullptr, 512, 512, 1024);
    gemm_f32<1, true ><<<dim3(2, 8), 256, 0, stream>>>(c1,     W2, b2, out_c2, s2p, nullptr, 512, 128, 512);
    gemm_f32<2, false><<<dim3(8, 8), 256, 0, stream>>>(out_c2, W2, b3, nullptr, nullptr, c3h, 512, 512, 128);
    recover_kernel<<<dim3(8, 4), 256, 0, stream>>>(c3h, W1T, br, out_rec);
    jac_kernel<<<dim3(8, 512), 256, 0, stream>>>(W2h, W1T, s1p, s2p, out_jac);
}

// Round 2
// 460.445 us; speedup vs baseline: 1.0112x; 1.0112x over previous
//
#include <hip/hip_runtime.h>

// Problem constants: B=512, D=1024, H1=512, H2=128
// Outputs (f32, concat): recover [512,1024], c2 [512,128], Jac [512,128,1024]
//
// Pipeline:
//  prep:     W1 f32 -> W1T f16 (transposed [1024][512]); W2 -> W2h f16
//  gemm_f32: c1 = sigmoid(x@W1^T+b1), s1p   (fp32, accuracy-critical)
//  gemm_f32: c2 = sigmoid(c1@W2^T+b2) -> out, s2p
//  gemm_f32: c3h = f16(sigmoid(c2@W2+b3))
//  mfma_bt<bias>: recover = c3@W1 + b_r -> out     (M=512,N=1024,K=512)
//  build_A:  A_all[b][h][k] = f16(s2p[b][h]*W2[h][k]*s1p[b][k])  (64 MB)
//  mfma_bt<nobias>: Jac[b] = A_all[b] @ W1T^T -> out  (batched, pure m97 GEMM)
//  (fallback fused jac_kernel if ws too small for A_all)

typedef _Float16 f16x8 __attribute__((ext_vector_type(8)));
typedef _Float16 f16x4 __attribute__((ext_vector_type(4)));
typedef float    f32x4 __attribute__((ext_vector_type(4)));
typedef float    f32x2 __attribute__((ext_vector_type(2)));

__device__ __forceinline__ void gld_lds16(const _Float16* src, _Float16* dst_wave_uniform) {
    // async global->LDS, 16B per lane; LDS dest = wave-uniform base + lane*16
    __builtin_amdgcn_global_load_lds((const __attribute__((address_space(1))) unsigned int*)src,
                                     (__attribute__((address_space(3))) unsigned int*)dst_wave_uniform,
                                     16, 0, 0);
}

// ---------------- prep: W1 transpose->f16, W2 ->f16 ----------------
__global__ __launch_bounds__(256) void prep_kernel(const float* __restrict__ W1,
                                                   const float* __restrict__ W2,
                                                   _Float16* __restrict__ W1T,   // [1024][512]
                                                   _Float16* __restrict__ W2h) { // [128][512]
    int bx = blockIdx.x;
    if (bx < 512) {
        __shared__ float tile[32][33];
        int dt = (bx & 31) * 32, kt = (bx >> 5) * 32;
        int tx = threadIdx.x & 31, ty = threadIdx.x >> 5;  // 32 x 8
        #pragma unroll
        for (int r = 0; r < 32; r += 8)
            tile[ty + r][tx] = W1[(kt + ty + r) * 1024 + dt + tx];
        __syncthreads();
        #pragma unroll
        for (int r = 0; r < 32; r += 8)
            W1T[(size_t)(dt + ty + r) * 512 + kt + tx] = (_Float16)tile[tx][ty + r];
    } else {
        int i = (bx - 512) * 1024 + threadIdx.x * 4;  // 64 blocks cover 65536
        f32x4 v = *(const f32x4*)(W2 + i);
        f16x4 h;
        h.x = (_Float16)v.x; h.y = (_Float16)v.y; h.z = (_Float16)v.z; h.w = (_Float16)v.w;
        *(f16x4*)(W2h + i) = h;
    }
}

// ---------------- small fp32 GEMMs (accuracy-critical path) ----------------
// 32x64 tile, 256 threads, per-thread 2x4. TRANSB=true: B is [N][K] (C=A@B^T).
// EPI: 1 = sigmoid -> C (f32) + Cd = s(1-s);  2 = sigmoid -> Ch (f16)
template <int EPI, bool TRANSB>
__global__ __launch_bounds__(256) void gemm_f32(const float* __restrict__ A,
                                                const float* __restrict__ Bm,
                                                const float* __restrict__ bias,
                                                float* __restrict__ C,
                                                float* __restrict__ Cd,
                                                _Float16* __restrict__ Ch,
                                                int M, int N, int K) {
    __shared__ __align__(16) float As[16][34];  // [k][m] (32 + pad)
    __shared__ __align__(16) float Bs[16][68];  // [k][n] (64 + pad)
    const int n0 = blockIdx.x * 64, m0 = blockIdx.y * 32;
    const int tid = threadIdx.x, tx = tid & 15, ty = tid >> 4;
    float acc[2][4] = {};

    for (int k0 = 0; k0 < K; k0 += 16) {
        #pragma unroll
        for (int r = 0; r < 2; ++r) {
            int m = (tid >> 4) + r * 16, k = tid & 15;
            As[k][m] = A[(size_t)(m0 + m) * K + k0 + k];
        }
        if (TRANSB) {
            #pragma unroll
            for (int r = 0; r < 4; ++r) {
                int n = (tid >> 4) + r * 16, k = tid & 15;
                Bs[k][n] = Bm[(size_t)(n0 + n) * K + k0 + k];
            }
        } else {
            #pragma unroll
            for (int r = 0; r < 4; ++r) {
                int k = (tid >> 6) + r * 4, n = tid & 63;
                Bs[k][n] = Bm[(size_t)(k0 + k) * N + n0 + n];
            }
        }
        __syncthreads();
        #pragma unroll
        for (int k = 0; k < 16; ++k) {
            f32x2 av = *(const f32x2*)&As[k][ty * 2];
            f32x4 bv = *(const f32x4*)&Bs[k][tx * 4];
            #pragma unroll
            for (int i = 0; i < 2; ++i)
                #pragma unroll
                for (int j = 0; j < 4; ++j)
                    acc[i][j] += av[i] * bv[j];
        }
        __syncthreads();
    }

    #pragma unroll
    for (int i = 0; i < 2; ++i) {
        int row = m0 + ty * 2 + i;
        #pragma unroll
        for (int j = 0; j < 4; ++j) {
            int col = n0 + tx * 4 + j;
            float z = acc[i][j] + bias[col];
            float s = 1.f / (1.f + __expf(-z));
            if constexpr (EPI == 1) {
                C[(size_t)row * N + col]  = s;
                Cd[(size_t)row * N + col] = s * (1.f - s);
            } else {
                Ch[(size_t)row * N + col] = (_Float16)s;
            }
        }
    }
}

// ---------------- build A_all[b][h][k] = f16(s2p[b][h]*W2[h][k]*s1p[b][k]) ----------------
__global__ __launch_bounds__(256) void build_A(const float* __restrict__ W2,
                                               const float* __restrict__ s1p,
                                               const float* __restrict__ s2p,
                                               _Float16* __restrict__ A_all) {
    const int b = blockIdx.x, tid = threadIdx.x;
    __shared__ float S1[512];
    __shared__ float S2[128];
    S1[tid]       = s1p[(size_t)b * 512 + tid];
    S1[tid + 256] = s1p[(size_t)b * 512 + tid + 256];
    if (tid < 128) S2[tid] = s2p[(size_t)b * 128 + tid];
    __syncthreads();
    _Float16* out = A_all + (size_t)b * 65536;
    #pragma unroll 4
    for (int i = 0; i < 32; ++i) {
        int c = tid + 256 * i;          // 8192 chunks of 8 elements
        int h = c >> 6, k8 = (c & 63) * 8;
        f32x4 w0 = *(const f32x4*)(W2 + h * 512 + k8);
        f32x4 w1 = *(const f32x4*)(W2 + h * 512 + k8 + 4);
        float s2 = S2[h];
        f16x8 o;
        o[0] = (_Float16)(s2 * w0.x * S1[k8 + 0]);
        o[1] = (_Float16)(s2 * w0.y * S1[k8 + 1]);
        o[2] = (_Float16)(s2 * w0.z * S1[k8 + 2]);
        o[3] = (_Float16)(s2 * w0.w * S1[k8 + 3]);
        o[4] = (_Float16)(s2 * w1.x * S1[k8 + 4]);
        o[5] = (_Float16)(s2 * w1.y * S1[k8 + 5]);
        o[6] = (_Float16)(s2 * w1.z * S1[k8 + 6]);
        o[7] = (_Float16)(s2 * w1.w * S1[k8 + 7]);
        *(f16x8*)(out + h * 512 + k8) = o;
    }
}

// ---------------- m97-pattern MFMA f16 GEMM: Out = A @ B^T (+bias) ----------------
// A [M][K] f16, Bmat [N][K] f16, Out [M][N] f32. 128x128 tile, K%64==0.
// blockIdx.z = batch (A += z*aBatch, Out += z*oBatch).
template <bool HAS_BIAS>
__global__ __launch_bounds__(256) void mfma_bt(const _Float16* __restrict__ Abase,
                                               const _Float16* __restrict__ Bmat,
                                               const float* __restrict__ bias,
                                               float* __restrict__ OutBase,
                                               int K, int N,
                                               long aBatch, long oBatch) {
    __shared__ __align__(16) _Float16 Asl[128 * 64];  // [m][k]
    __shared__ __align__(16) _Float16 Bsl[128 * 64];  // [n][k]
    __shared__ float Bias[128];
    const _Float16* A = Abase + (size_t)blockIdx.z * aBatch;
    float* Out = OutBase + (size_t)blockIdx.z * oBatch;
    const int m0 = blockIdx.y * 128, n0 = blockIdx.x * 128;
    const int tid = threadIdx.x;
    const int lane = tid & 63, wave = tid >> 6;
    const int wm = (wave >> 1) * 64, wn = (wave & 1) * 64;
    const int l15 = lane & 15, q = lane >> 4;

    if (HAS_BIAS && tid < 128) Bias[tid] = bias[n0 + tid];

    f32x4 acc[4][4];
    #pragma unroll
    for (int i = 0; i < 4; ++i)
        #pragma unroll
        for (int j = 0; j < 4; ++j) acc[i][j] = (f32x4){0.f, 0.f, 0.f, 0.f};

    const int rbase = wave * 8 + (lane >> 3);
    const int kof   = (lane & 7) * 8;

    for (int k0 = 0; k0 < K; k0 += 64) {
        #pragma unroll
        for (int r = 0; r < 4; ++r) {
            gld_lds16(A    + (size_t)(m0 + r * 32 + rbase) * K + k0 + kof, Asl + (r * 32 + wave * 8) * 64);
            gld_lds16(Bmat + (size_t)(n0 + r * 32 + rbase) * K + k0 + kof, Bsl + (r * 32 + wave * 8) * 64);
        }
        __syncthreads();
        #pragma unroll
        for (int kk = 0; kk < 64; kk += 32) {
            f16x8 af[4], bf[4];
            #pragma unroll
            for (int i = 0; i < 4; ++i)
                af[i] = *(const f16x8*)(Asl + (wm + i * 16 + l15) * 64 + kk + q * 8);
            #pragma unroll
            for (int j = 0; j < 4; ++j)
                bf[j] = *(const f16x8*)(Bsl + (wn + j * 16 + l15) * 64 + kk + q * 8);
            #pragma unroll
            for (int i = 0; i < 4; ++i)
                #pragma unroll
                for (int j = 0; j < 4; ++j)
                    acc[i][j] = __builtin_amdgcn_mfma_f32_16x16x32_f16(af[i], bf[j], acc[i][j], 0, 0, 0);
        }
        __syncthreads();
    }

    #pragma unroll
    for (int i = 0; i < 4; ++i) {
        #pragma unroll
        for (int rg = 0; rg < 4; ++rg) {
            int m = m0 + wm + i * 16 + q * 4 + rg;
            #pragma unroll
            for (int j = 0; j < 4; ++j) {
                int dcol = wn + j * 16 + l15;
                float v = acc[i][j][rg];
                if (HAS_BIAS) v += Bias[dcol];
                Out[(size_t)m * N + n0 + dcol] = v;
            }
        }
    }
}

// ---------------- fallback fused Jacobian (used only if ws too small) ----------------
__global__ __launch_bounds__(256) void jac_kernel(const _Float16* __restrict__ W2h,
                                                  const _Float16* __restrict__ W1T,
                                                  const float* __restrict__ s1p,
                                                  const float* __restrict__ s2p,
                                                  float* __restrict__ Jac) {
    __shared__ __align__(16) _Float16 Asl[128 * 64];
    __shared__ __align__(16) _Float16 Bsl[128 * 64];
    __shared__ float Ssl[128];
    const int b  = blockIdx.y;
    const int n0 = blockIdx.x * 128;
    const int tid = threadIdx.x;
    const int lane = tid & 63, wave = tid >> 6;
    const int wm = (wave >> 1) * 64, wn = (wave & 1) * 64;
    const int l15 = lane & 15, q = lane >> 4;

    if (tid < 128) Ssl[tid] = s2p[b * 128 + tid];

    f32x4 acc[4][4];
    #pragma unroll
    for (int i = 0; i < 4; ++i)
        #pragma unroll
        for (int j = 0; j < 4; ++j) acc[i][j] = (f32x4){0.f, 0.f, 0.f, 0.f};

    const int ah  = tid >> 4;
    const int akq = (tid & 15) * 4;
    const int rbase = wave * 8 + (lane >> 3);
    const int kof   = (lane & 7) * 8;

    for (int k0 = 0; k0 < 512; k0 += 64) {
        f32x4 s4 = *(const f32x4*)(s1p + (size_t)b * 512 + k0 + akq);
        f16x4 s4h;
        s4h.x = (_Float16)s4.x; s4h.y = (_Float16)s4.y;
        s4h.z = (_Float16)s4.z; s4h.w = (_Float16)s4.w;
        #pragma unroll
        for (int r = 0; r < 8; ++r) {
            int h = ah + r * 16;
            f16x4 w4 = *(const f16x4*)(W2h + (size_t)h * 512 + k0 + akq);
            *(f16x4*)(Asl + h * 64 + akq) = w4 * s4h;
        }
        #pragma unroll
        for (int r = 0; r < 4; ++r)
            gld_lds16(W1T + (size_t)(n0 + r * 32 + rbase) * 512 + k0 + kof,
                      Bsl + (r * 32 + wave * 8) * 64);
        __syncthreads();

        #pragma unroll
        for (int kk = 0; kk < 64; kk += 32) {
            f16x8 af[4], bf[4];
            #pragma unroll
            for (int i = 0; i < 4; ++i)
                af[i] = *(const f16x8*)(Asl + (wm + i * 16 + l15) * 64 + kk + q * 8);
            #pragma unroll
            for (int j = 0; j < 4; ++j)
                bf[j] = *(const f16x8*)(Bsl + (wn + j * 16 + l15) * 64 + kk + q * 8);
            #pragma unroll
            for (int i = 0; i < 4; ++i)
                #pragma unroll
                for (int j = 0; j < 4; ++j)
                    acc[i][j] = __builtin_amdgcn_mfma_f32_16x16x32_f16(af[i], bf[j], acc[i][j], 0, 0, 0);
        }
        __syncthreads();
    }

    float* outb = Jac + (size_t)b * (128 * 1024);
    #pragma unroll
    for (int i = 0; i < 4; ++i) {
        #pragma unroll
        for (int rg = 0; rg < 4; ++rg) {
            int h = wm + i * 16 + q * 4 + rg;
            float s = Ssl[h];
            #pragma unroll
            for (int j = 0; j < 4; ++j) {
                int d = n0 + wn + j * 16 + l15;
                outb[(size_t)h * 1024 + d] = acc[i][j][rg] * s;
            }
        }
    }
}

extern "C" void kernel_launch(void* const* d_in, const int* in_sizes, int n_in,
                              void* d_out, int out_size, void* d_ws, size_t ws_size,
                              hipStream_t stream) {
    const float* x  = (const float*)d_in[0];
    const float* W1 = (const float*)d_in[1];
    const float* b1 = (const float*)d_in[2];
    const float* W2 = (const float*)d_in[3];
    const float* b2 = (const float*)d_in[4];
    const float* b3 = (const float*)d_in[5];
    const float* br = (const float*)d_in[6];

    float* out_rec = (float*)d_out;               // 512*1024
    float* out_c2  = out_rec + 512 * 1024;        // 512*128
    float* out_jac = out_c2 + 512 * 128;          // 512*128*1024

    char* ws = (char*)d_ws;
    _Float16* W1T   = (_Float16*)(ws);             // 1 MB   [1024][512]
    _Float16* W2h   = (_Float16*)(ws + 0x100000);  // 128 KB [128][512]
    float*    c1    = (float*)(ws + 0x120000);     // 1 MB
    float*    s1p   = (float*)(ws + 0x220000);     // 1 MB
    float*    s2p   = (float*)(ws + 0x320000);     // 256 KB
    _Float16* c3h   = (_Float16*)(ws + 0x360000);  // 512 KB (ends 0x3E0000)
    _Float16* A_all = (_Float16*)(ws + 0x400000);  // 64 MB  [512][128][512]
    const bool big_ws = ws_size >= (size_t)0x4400000;

    prep_kernel<<<576, 256, 0, stream>>>(W1, W2, W1T, W2h);
    gemm_f32<1, true ><<<dim3(8, 16), 256, 0, stream>>>(x,      W1, b1, c1,     s1p, nullptr, 512, 512, 1024);
    gemm_f32<1, true ><<<dim3(2, 16), 256, 0, stream>>>(c1,     W2, b2, out_c2, s2p, nullptr, 512, 128, 512);
    gemm_f32<2, false><<<dim3(8, 16), 256, 0, stream>>>(out_c2, W2, b3, nullptr, nullptr, c3h, 512, 512, 128);
    mfma_bt<true><<<dim3(8, 4, 1), 256, 0, stream>>>(c3h, W1T, br, out_rec, 512, 1024, 0, 0);
    if (big_ws) {
        build_A<<<512, 256, 0, stream>>>(W2, s1p, s2p, A_all);
        mfma_bt<false><<<dim3(8, 1, 512), 256, 0, stream>>>(A_all, W1T, nullptr, out_jac,
                                                            512, 1024, 65536, 131072);
    } else {
        jac_kernel<<<dim3(8, 512), 256, 0, stream>>>(W2h, W1T, s1p, s2p, out_jac);
    }
}